// Round 1
// baseline (1599.354 us; speedup 1.0000x reference)
//
#include <hip/hip_runtime.h>
#include <hip/hip_bf16.h>

// Problem constants
#define B_   64
#define T_   300
#define NIN  2312
#define H1   512
#define H2   256
#define NOUT 101

// ---------------- transpose helper (tiny, perf-irrelevant) ----------------
__global__ void transpose_k(const float* __restrict__ src, float* __restrict__ dst,
                            int R, int C) {
    int idx = blockIdx.x * 256 + threadIdx.x;
    if (idx < R * C) {
        int r = idx / C, c = idx % C;
        dst[c * R + r] = src[r * C + c];
    }
}

// ---------------- feed-forward GEMM: Y[M][N] = X[M][K] * W[N][K]^T ----------------
// M=19200, K=2312, N=512. fp32 vector FMA (no fp32 MFMA on CDNA4).
#define GBM 128
#define GBN 128
#define GBK 16

__global__ __launch_bounds__(256) void gemm_ff(const float* __restrict__ X,
                                               const float* __restrict__ W,
                                               float* __restrict__ Y) {
    const int K = NIN, N = H1;
    __shared__ float As[GBK][GBM + 4];
    __shared__ float Bs[GBK][GBN + 4];

    const int bn = blockIdx.x;   // 0..3
    const int bm = blockIdx.y;   // 0..149
    const int tid = threadIdx.x;
    const int tx = tid & 15, ty = tid >> 4;
    const int m0 = bm * GBM, n0 = bn * GBN;

    float acc[8][8] = {};

    for (int k0 = 0; k0 < K; k0 += GBK) {
#pragma unroll
        for (int l = 0; l < 8; ++l) {
            int idx = l * 256 + tid;
            int kk = idx & 15, r = idx >> 4;
            int kg = k0 + kk;
            As[kk][r] = (kg < K) ? X[(size_t)(m0 + r) * K + kg] : 0.f;
        }
#pragma unroll
        for (int l = 0; l < 8; ++l) {
            int idx = l * 256 + tid;
            int kk = idx & 15, r = idx >> 4;
            int kg = k0 + kk;
            Bs[kk][r] = (kg < K) ? W[(size_t)(n0 + r) * K + kg] : 0.f;
        }
        __syncthreads();
#pragma unroll
        for (int kk = 0; kk < GBK; ++kk) {
            float a[8], b[8];
#pragma unroll
            for (int i = 0; i < 8; ++i) a[i] = As[kk][ty * 8 + i];
#pragma unroll
            for (int j = 0; j < 8; ++j) b[j] = Bs[kk][tx * 8 + j];
#pragma unroll
            for (int i = 0; i < 8; ++i)
#pragma unroll
                for (int j = 0; j < 8; ++j)
                    acc[i][j] = fmaf(a[i], b[j], acc[i][j]);
        }
        __syncthreads();
    }

#pragma unroll
    for (int i = 0; i < 8; ++i)
#pragma unroll
        for (int j = 0; j < 8; ++j)
            Y[(size_t)(m0 + ty * 8 + i) * N + n0 + tx * 8 + j] = acc[i][j];
}

// ---------------- persistent per-batch SNN scan ----------------
// One block per batch element, 512 threads (thread h = layer-1 neuron h).
// Spike matmuls are sparse row-gathers driven by 64-bit ballot masks in LDS.
__global__ __launch_bounds__(512) void snn_scan(
    const float* __restrict__ I1ff,   // [B][T][H1]
    const float* __restrict__ wrt,    // [H1][H1]  wrt[i][h] = w_rec[h][i]
    const float* __restrict__ w2t,    // [H1][H2]  w2t[i][j] = w2[j][i]
    const float* __restrict__ w3t,    // [H2][NOUT] w3t[i][j] = w3[j][i]
    const float* __restrict__ alpha1, const float* __restrict__ rho1,
    const float* __restrict__ beta_a1,
    const float* __restrict__ alpha2, const float* __restrict__ rho2,
    const float* __restrict__ beta_a2,
    const float* __restrict__ beta_out,
    float* __restrict__ out)          // [B][NOUT]
{
    const int b = blockIdx.x;
    const int h = threadIdx.x;
    const int wave = h >> 6, lane = h & 63;

    __shared__ unsigned long long Bal1[8];  // layer-1 spike mask (512 bits)
    __shared__ unsigned long long Bal2[4];  // layer-2 spike mask (256 bits)

    // per-thread state
    float v1 = 0.f, a1 = 0.f, s1 = 0.f;
    const float al1 = alpha1[h], rh1 = rho1[h], ba1 = beta_a1[h];

    float v2 = 0.f, a2 = 0.f, s2 = 0.f;
    float al2 = 0.f, rh2 = 0.f, ba2 = 0.f;
    if (h < H2) { al2 = alpha2[h]; rh2 = rho2[h]; ba2 = beta_a2[h]; }

    float vo = 0.f, vsum = 0.f, bo = 0.f;
    if (h < NOUT) bo = beta_out[h];

    if (h < 8) Bal1[h] = 0ull;
    if (h < 4) Bal2[h] = 0ull;
    __syncthreads();

    const float* I1p = I1ff + (size_t)b * T_ * H1;

    for (int t = 0; t < T_; ++t) {
        // ---- phase 1: layer-1 adaptive LIF with recurrent input ----
        float rec = 0.f;
#pragma unroll
        for (int w = 0; w < 8; ++w) {
            unsigned long long bits = Bal1[w];
            while (bits) {
                int i = (w << 6) + __builtin_ctzll(bits);
                bits &= bits - 1;
                rec += wrt[i * H1 + h];
            }
        }
        float I1 = I1p[t * H1 + h] + rec;
        float v1n = al1 * v1 + (1.f - al1) * (I1 - a1);
        float sp1 = (v1n > 1.f) ? 1.f : 0.f;
        v1 = v1n - sp1;                 // soft reset (THR=1)
        a1 = rh1 * a1 + ba1 * s1;       // adaptation uses PREVIOUS spike
        s1 = sp1;

        __syncthreads();                // A: everyone done reading Bal1
        unsigned long long m1 = __ballot(sp1 > 0.f);
        if (lane == 0) Bal1[wave] = m1;
        __syncthreads();                // B: new Bal1 visible

        // ---- phase 2: layer-2 adaptive LIF (input = new layer-1 spikes) ----
        if (h < H2) {                   // waves 0..3, wave-aligned
            float I2 = 0.f;
#pragma unroll
            for (int w = 0; w < 8; ++w) {
                unsigned long long bits = Bal1[w];
                while (bits) {
                    int i = (w << 6) + __builtin_ctzll(bits);
                    bits &= bits - 1;
                    I2 += w2t[i * H2 + h];
                }
            }
            float v2n = al2 * v2 + (1.f - al2) * (I2 - a2);
            float sp2 = (v2n > 1.f) ? 1.f : 0.f;
            v2 = v2n - sp2;
            a2 = rh2 * a2 + ba2 * s2;   // uses PREVIOUS layer-2 spike
            s2 = sp2;
            unsigned long long m2 = __ballot(sp2 > 0.f);
            if (lane == 0) Bal2[wave] = m2;
        }
        __syncthreads();                // C: Bal2 visible

        // ---- phase 3: leaky-integrator readout ----
        if (h < NOUT) {
            float io = 0.f;
#pragma unroll
            for (int w = 0; w < 4; ++w) {
                unsigned long long bits = Bal2[w];
                while (bits) {
                    int i = (w << 6) + __builtin_ctzll(bits);
                    bits &= bits - 1;
                    io += w3t[i * NOUT + h];
                }
            }
            vo = bo * vo + (1.f - bo) * io;
            vsum += vo;
        }
        // no trailing sync needed: next step's sync A orders phase-3 reads
        // of Bal2 before the next overwrite.
    }

    if (h < NOUT) out[b * NOUT + h] = vsum * (1.f / (float)T_);
}

// ---------------- launch ----------------
extern "C" void kernel_launch(void* const* d_in, const int* in_sizes, int n_in,
                              void* d_out, int out_size, void* d_ws, size_t ws_size,
                              hipStream_t stream) {
    const float* x      = (const float*)d_in[0];   // [B][T][NIN]
    const float* w1     = (const float*)d_in[1];   // [H1][NIN]
    const float* w_rec  = (const float*)d_in[2];   // [H1][H1]
    const float* w2     = (const float*)d_in[3];   // [H2][H1]
    const float* w3     = (const float*)d_in[4];   // [NOUT][H2]
    const float* alpha1 = (const float*)d_in[5];
    const float* rho1   = (const float*)d_in[6];
    const float* beta_a1= (const float*)d_in[7];
    const float* alpha2 = (const float*)d_in[8];
    const float* rho2   = (const float*)d_in[9];
    const float* beta_a2= (const float*)d_in[10];
    const float* beta_out=(const float*)d_in[11];
    float* out = (float*)d_out;

    float* ws   = (float*)d_ws;
    float* I1ff = ws;                                   // 64*300*512 = 9,830,400 f
    float* wrt  = I1ff + (size_t)B_ * T_ * H1;          // 262,144 f
    float* w2t  = wrt + H1 * H1;                        // 131,072 f
    float* w3t  = w2t + H1 * H2;                        // 25,856 f

    // weight transposes (coalesced gathers in the scan)
    transpose_k<<<(H1 * H1 + 255) / 256, 256, 0, stream>>>(w_rec, wrt, H1, H1);
    transpose_k<<<(H2 * H1 + 255) / 256, 256, 0, stream>>>(w2, w2t, H2, H1);
    transpose_k<<<(NOUT * H2 + 255) / 256, 256, 0, stream>>>(w3, w3t, NOUT, H2);

    // feed-forward GEMM: I1ff[(b*T+t)][h] = sum_n x[b,t,n] * w1[h,n]
    dim3 gg(H1 / GBN, (B_ * T_) / GBM);   // (4, 150)
    gemm_ff<<<gg, 256, 0, stream>>>(x, w1, I1ff);

    // sequential scan, one block per batch element
    snn_scan<<<B_, 512, 0, stream>>>(I1ff, wrt, w2t, w3t,
                                     alpha1, rho1, beta_a1,
                                     alpha2, rho2, beta_a2,
                                     beta_out, out);
}

// Round 2
// 598.710 us; speedup vs baseline: 2.6713x; 2.6713x over previous
//
#include <hip/hip_runtime.h>
#include <hip/hip_bf16.h>
#include <stdint.h>

// Problem constants
#define B_   64
#define T_   300
#define NIN  2312
#define H1   512
#define H2   256
#define NOUT 101
#define KP   2368   // NIN padded up to a multiple of 64 (2368 = 37*64)

typedef __attribute__((ext_vector_type(8))) short bf16x8;
typedef __attribute__((ext_vector_type(4))) float f32x4;
typedef __attribute__((ext_vector_type(8))) unsigned short u16x8;

// ---------------- transpose helper (tiny, perf-irrelevant) ----------------
__global__ void transpose_k(const float* __restrict__ src, float* __restrict__ dst,
                            int R, int C) {
    int idx = blockIdx.x * 256 + threadIdx.x;
    if (idx < R * C) {
        int r = idx / C, c = idx % C;
        dst[c * R + r] = src[r * C + c];
    }
}

// ---------------- fp32 -> bf16 (RNE) with K-padding ----------------
__global__ __launch_bounds__(256) void cvt_pad_bf16(const float* __restrict__ src,
                                                    unsigned short* __restrict__ dst,
                                                    int R, int C, int Cp) {
    int idx = blockIdx.x * 256 + threadIdx.x;
    int cpw = Cp >> 3;
    if (idx >= R * cpw) return;
    int row = idx / cpw;
    int c0 = (idx - row * cpw) << 3;
    const float* s = src + (size_t)row * C + c0;
    u16x8 o;
#pragma unroll
    for (int j = 0; j < 8; ++j) {
        int k = c0 + j;
        float v = (k < C) ? s[j] : 0.f;
        union { float f; unsigned u; } cv; cv.f = v;
        unsigned r = (cv.u + 0x7fff + ((cv.u >> 16) & 1)) >> 16;  // RNE
        o[j] = (unsigned short)r;
    }
    *(u16x8*)(dst + (size_t)row * Cp + c0) = o;
}

// ---------------- bf16 MFMA GEMM (m97 structure) ----------------
// Y[M][H1] = Xb[M][KP] * Wb[H1][KP]^T ; 128x128 tile, BK=64, 4 waves (2x2),
// each wave 64x64 output = 4x4 frags of 16x16x32 MFMA.
#define LDS_GLOAD16(g, l) \
  __builtin_amdgcn_global_load_lds((const __attribute__((address_space(1))) void*)(g), \
                                   (__attribute__((address_space(3))) void*)(l), 16, 0, 0)

__global__ __launch_bounds__(256) void gemm_bf16(
    const unsigned short* __restrict__ Xb,   // [M][KP] bf16 bits
    const unsigned short* __restrict__ Wb,   // [H1][KP] bf16 bits
    float* __restrict__ Y)                   // [M][H1]
{
    __shared__ __align__(16) unsigned short As[128][64];
    __shared__ __align__(16) unsigned short Bs[128][64];

    const int tid  = threadIdx.x;
    const int wave = tid >> 6, lane = tid & 63;
    const int wr = wave >> 1, wc = wave & 1;          // 2x2 waves, 64x64 each
    const int m0 = blockIdx.y * 128, n0 = blockIdx.x * 128;
    const int fr = lane & 15, fq = lane >> 4;

    f32x4 acc[4][4] = {};

    // staging: each wave fills 32 rows of As and Bs; 1 instr = 64 lanes * 16B
    // = 1024B = 8 rows of 128B. Global src per-lane; LDS dest wave-uniform.
    const size_t rowB = (size_t)KP * 2;
    const char* gA = (const char*)Xb + (size_t)(m0 + 32 * wave + (lane >> 3)) * rowB + (lane & 7) * 16;
    const char* gB = (const char*)Wb + (size_t)(n0 + 32 * wave + (lane >> 3)) * rowB + (lane & 7) * 16;
    unsigned short* lA = &As[32 * wave][0];
    unsigned short* lB = &Bs[32 * wave][0];

    for (int kt = 0; kt < KP / 64; ++kt) {
        const size_t ko = (size_t)kt * 128;           // byte offset along K
#pragma unroll
        for (int s = 0; s < 4; ++s) {
            LDS_GLOAD16(gA + ko + (size_t)s * 8 * rowB, lA + s * 8 * 64);
            LDS_GLOAD16(gB + ko + (size_t)s * 8 * rowB, lB + s * 8 * 64);
        }
        __syncthreads();   // drains vmcnt before barrier (compiler-inserted)
#pragma unroll
        for (int ks = 0; ks < 2; ++ks) {
            bf16x8 a[4], b[4];
#pragma unroll
            for (int mi = 0; mi < 4; ++mi)
                a[mi] = *(const bf16x8*)&As[wr * 64 + mi * 16 + fr][ks * 32 + fq * 8];
#pragma unroll
            for (int nj = 0; nj < 4; ++nj)
                b[nj] = *(const bf16x8*)&Bs[wc * 64 + nj * 16 + fr][ks * 32 + fq * 8];
#pragma unroll
            for (int mi = 0; mi < 4; ++mi)
#pragma unroll
                for (int nj = 0; nj < 4; ++nj)
                    acc[mi][nj] = __builtin_amdgcn_mfma_f32_16x16x32_bf16(
                        a[mi], b[nj], acc[mi][nj], 0, 0, 0);
        }
        __syncthreads();
    }

    // C/D layout (m89-verified): col = lane&15, row = (lane>>4)*4 + reg
#pragma unroll
    for (int mi = 0; mi < 4; ++mi)
#pragma unroll
        for (int nj = 0; nj < 4; ++nj) {
            int r0 = m0 + wr * 64 + mi * 16 + fq * 4;
            int c  = n0 + wc * 64 + nj * 16 + fr;
#pragma unroll
            for (int r = 0; r < 4; ++r)
                Y[(size_t)(r0 + r) * H1 + c] = acc[mi][nj][r];
        }
}

// ---------------- fp32 fallback GEMM (used only if ws too small) ----------------
#define GBM 128
#define GBN 128
#define GBK 16
__global__ __launch_bounds__(256) void gemm_ff(const float* __restrict__ X,
                                               const float* __restrict__ W,
                                               float* __restrict__ Y) {
    const int K = NIN, N = H1;
    __shared__ float As[GBK][GBM + 4];
    __shared__ float Bs[GBK][GBN + 4];
    const int bn = blockIdx.x, bm = blockIdx.y;
    const int tid = threadIdx.x;
    const int tx = tid & 15, ty = tid >> 4;
    const int m0 = bm * GBM, n0 = bn * GBN;
    float acc[8][8] = {};
    for (int k0 = 0; k0 < K; k0 += GBK) {
#pragma unroll
        for (int l = 0; l < 8; ++l) {
            int idx = l * 256 + tid;
            int kk = idx & 15, r = idx >> 4;
            int kg = k0 + kk;
            As[kk][r] = (kg < K) ? X[(size_t)(m0 + r) * K + kg] : 0.f;
        }
#pragma unroll
        for (int l = 0; l < 8; ++l) {
            int idx = l * 256 + tid;
            int kk = idx & 15, r = idx >> 4;
            int kg = k0 + kk;
            Bs[kk][r] = (kg < K) ? W[(size_t)(n0 + r) * K + kg] : 0.f;
        }
        __syncthreads();
#pragma unroll
        for (int kk = 0; kk < GBK; ++kk) {
            float a[8], b[8];
#pragma unroll
            for (int i = 0; i < 8; ++i) a[i] = As[kk][ty * 8 + i];
#pragma unroll
            for (int j = 0; j < 8; ++j) b[j] = Bs[kk][tx * 8 + j];
#pragma unroll
            for (int i = 0; i < 8; ++i)
#pragma unroll
                for (int j = 0; j < 8; ++j)
                    acc[i][j] = fmaf(a[i], b[j], acc[i][j]);
        }
        __syncthreads();
    }
#pragma unroll
    for (int i = 0; i < 8; ++i)
#pragma unroll
        for (int j = 0; j < 8; ++j)
            Y[(size_t)(m0 + ty * 8 + i) * N + n0 + tx * 8 + j] = acc[i][j];
}

// ---------------- persistent per-batch SNN scan ----------------
__global__ __launch_bounds__(512) void snn_scan(
    const float* __restrict__ I1ff,   // [B][T][H1]
    const float* __restrict__ wrt,    // [H1][H1]  wrt[i][h] = w_rec[h][i]
    const float* __restrict__ w2t,    // [H1][H2]
    const float* __restrict__ w3t,    // [H2][NOUT]
    const float* __restrict__ alpha1, const float* __restrict__ rho1,
    const float* __restrict__ beta_a1,
    const float* __restrict__ alpha2, const float* __restrict__ rho2,
    const float* __restrict__ beta_a2,
    const float* __restrict__ beta_out,
    float* __restrict__ out)          // [B][NOUT]
{
    const int b = blockIdx.x;
    const int h = threadIdx.x;
    const int wave = h >> 6, lane = h & 63;

    __shared__ unsigned long long Bal1[8];
    __shared__ unsigned long long Bal2[4];

    float v1 = 0.f, a1 = 0.f, s1 = 0.f;
    const float al1 = alpha1[h], rh1 = rho1[h], ba1 = beta_a1[h];

    float v2 = 0.f, a2 = 0.f, s2 = 0.f;
    float al2 = 0.f, rh2 = 0.f, ba2 = 0.f;
    if (h < H2) { al2 = alpha2[h]; rh2 = rho2[h]; ba2 = beta_a2[h]; }

    float vo = 0.f, vsum = 0.f, bo = 0.f;
    if (h < NOUT) bo = beta_out[h];

    if (h < 8) Bal1[h] = 0ull;
    if (h < 4) Bal2[h] = 0ull;
    __syncthreads();

    const float* I1p = I1ff + (size_t)b * T_ * H1;

    for (int t = 0; t < T_; ++t) {
        float rec = 0.f;
#pragma unroll
        for (int w = 0; w < 8; ++w) {
            unsigned long long bits = Bal1[w];
            while (bits) {
                int i = (w << 6) + __builtin_ctzll(bits);
                bits &= bits - 1;
                rec += wrt[i * H1 + h];
            }
        }
        float I1 = I1p[t * H1 + h] + rec;
        float v1n = al1 * v1 + (1.f - al1) * (I1 - a1);
        float sp1 = (v1n > 1.f) ? 1.f : 0.f;
        v1 = v1n - sp1;
        a1 = rh1 * a1 + ba1 * s1;
        s1 = sp1;

        __syncthreads();
        unsigned long long m1 = __ballot(sp1 > 0.f);
        if (lane == 0) Bal1[wave] = m1;
        __syncthreads();

        if (h < H2) {
            float I2 = 0.f;
#pragma unroll
            for (int w = 0; w < 8; ++w) {
                unsigned long long bits = Bal1[w];
                while (bits) {
                    int i = (w << 6) + __builtin_ctzll(bits);
                    bits &= bits - 1;
                    I2 += w2t[i * H2 + h];
                }
            }
            float v2n = al2 * v2 + (1.f - al2) * (I2 - a2);
            float sp2 = (v2n > 1.f) ? 1.f : 0.f;
            v2 = v2n - sp2;
            a2 = rh2 * a2 + ba2 * s2;
            s2 = sp2;
            unsigned long long m2 = __ballot(sp2 > 0.f);
            if (lane == 0) Bal2[wave] = m2;
        }
        __syncthreads();

        if (h < NOUT) {
            float io = 0.f;
#pragma unroll
            for (int w = 0; w < 4; ++w) {
                unsigned long long bits = Bal2[w];
                while (bits) {
                    int i = (w << 6) + __builtin_ctzll(bits);
                    bits &= bits - 1;
                    io += w3t[i * NOUT + h];
                }
            }
            vo = bo * vo + (1.f - bo) * io;
            vsum += vo;
        }
    }

    if (h < NOUT) out[b * NOUT + h] = vsum * (1.f / (float)T_);
}

// ---------------- launch ----------------
extern "C" void kernel_launch(void* const* d_in, const int* in_sizes, int n_in,
                              void* d_out, int out_size, void* d_ws, size_t ws_size,
                              hipStream_t stream) {
    const float* x      = (const float*)d_in[0];   // [B][T][NIN]
    const float* w1     = (const float*)d_in[1];   // [H1][NIN]
    const float* w_rec  = (const float*)d_in[2];   // [H1][H1]
    const float* w2     = (const float*)d_in[3];   // [H2][H1]
    const float* w3     = (const float*)d_in[4];   // [NOUT][H2]
    const float* alpha1 = (const float*)d_in[5];
    const float* rho1   = (const float*)d_in[6];
    const float* beta_a1= (const float*)d_in[7];
    const float* alpha2 = (const float*)d_in[8];
    const float* rho2   = (const float*)d_in[9];
    const float* beta_a2= (const float*)d_in[10];
    const float* beta_out=(const float*)d_in[11];
    float* out = (float*)d_out;

    const int M = B_ * T_;                         // 19200

    // workspace layout (256B-aligned chunks)
    size_t off = 0;
    auto take = [&](size_t bytes) {
        void* p = (char*)d_ws + off;
        off += (bytes + 255) & ~(size_t)255;
        return p;
    };
    float* I1ff = (float*)take((size_t)M * H1 * 4);            // 39.3 MB
    float* wrt  = (float*)take((size_t)H1 * H1 * 4);
    float* w2t  = (float*)take((size_t)H1 * H2 * 4);
    float* w3t  = (float*)take((size_t)H2 * NOUT * 4);
    size_t base_off = off;
    unsigned short* xb  = (unsigned short*)take((size_t)M * KP * 2);   // 90.9 MB
    unsigned short* w1b = (unsigned short*)take((size_t)H1 * KP * 2);  // 2.4 MB
    bool use_bf16 = (off <= ws_size);
    (void)base_off;

    // weight transposes for the scan's row-gathers
    transpose_k<<<(H1 * H1 + 255) / 256, 256, 0, stream>>>(w_rec, wrt, H1, H1);
    transpose_k<<<(H2 * H1 + 255) / 256, 256, 0, stream>>>(w2, w2t, H2, H1);
    transpose_k<<<(NOUT * H2 + 255) / 256, 256, 0, stream>>>(w3, w3t, NOUT, H2);

    if (use_bf16) {
        // bf16 conversions (K padded to KP with zeros)
        int nx = M * (KP / 8);
        cvt_pad_bf16<<<(nx + 255) / 256, 256, 0, stream>>>(x, xb, M, NIN, KP);
        int nw = H1 * (KP / 8);
        cvt_pad_bf16<<<(nw + 255) / 256, 256, 0, stream>>>(w1, w1b, H1, NIN, KP);

        dim3 gg(H1 / 128, M / 128);   // (4, 150)
        gemm_bf16<<<gg, 256, 0, stream>>>(xb, w1b, I1ff);
    } else {
        dim3 gg(H1 / GBN, M / GBM);
        gemm_ff<<<gg, 256, 0, stream>>>(x, w1, I1ff);
    }

    snn_scan<<<B_, 512, 0, stream>>>(I1ff, wrt, w2t, w3t,
                                     alpha1, rho1, beta_a1,
                                     alpha2, rho2, beta_a2,
                                     beta_out, out);
}

// Round 3
// 491.278 us; speedup vs baseline: 3.2555x; 1.2187x over previous
//
#include <hip/hip_runtime.h>
#include <hip/hip_bf16.h>
#include <stdint.h>

// Problem constants
#define B_   64
#define T_   300
#define NIN  2312
#define H1   512
#define H2   256
#define NOUT 101
#define KP   2368   // NIN padded up to a multiple of 64 (2368 = 37*64)

typedef __attribute__((ext_vector_type(8))) short bf16x8;
typedef __attribute__((ext_vector_type(4))) float f32x4;
typedef __attribute__((ext_vector_type(8))) unsigned short u16x8;

// ---------------- transpose helper (tiny, perf-irrelevant) ----------------
__global__ void transpose_k(const float* __restrict__ src, float* __restrict__ dst,
                            int R, int C) {
    int idx = blockIdx.x * 256 + threadIdx.x;
    if (idx < R * C) {
        int r = idx / C, c = idx % C;
        dst[c * R + r] = src[r * C + c];
    }
}

// ---------------- fp32 -> bf16 (RNE) with K-padding ----------------
__global__ __launch_bounds__(256) void cvt_pad_bf16(const float* __restrict__ src,
                                                    unsigned short* __restrict__ dst,
                                                    int R, int C, int Cp) {
    int idx = blockIdx.x * 256 + threadIdx.x;
    int cpw = Cp >> 3;
    if (idx >= R * cpw) return;
    int row = idx / cpw;
    int c0 = (idx - row * cpw) << 3;
    const float* s = src + (size_t)row * C + c0;
    u16x8 o;
#pragma unroll
    for (int j = 0; j < 8; ++j) {
        int k = c0 + j;
        float v = (k < C) ? s[j] : 0.f;
        union { float f; unsigned u; } cv; cv.f = v;
        unsigned r = (cv.u + 0x7fff + ((cv.u >> 16) & 1)) >> 16;  // RNE
        o[j] = (unsigned short)r;
    }
    *(u16x8*)(dst + (size_t)row * Cp + c0) = o;
}

// ---------------- bf16 MFMA GEMM (m97 structure) ----------------
#define LDS_GLOAD16(g, l) \
  __builtin_amdgcn_global_load_lds((const __attribute__((address_space(1))) void*)(g), \
                                   (__attribute__((address_space(3))) void*)(l), 16, 0, 0)

__global__ __launch_bounds__(256) void gemm_bf16(
    const unsigned short* __restrict__ Xb,   // [M][KP] bf16 bits
    const unsigned short* __restrict__ Wb,   // [H1][KP] bf16 bits
    float* __restrict__ Y)                   // [M][H1]
{
    __shared__ __align__(16) unsigned short As[128][64];
    __shared__ __align__(16) unsigned short Bs[128][64];

    const int tid  = threadIdx.x;
    const int wave = tid >> 6, lane = tid & 63;
    const int wr = wave >> 1, wc = wave & 1;          // 2x2 waves, 64x64 each
    const int m0 = blockIdx.y * 128, n0 = blockIdx.x * 128;
    const int fr = lane & 15, fq = lane >> 4;

    f32x4 acc[4][4] = {};

    const size_t rowB = (size_t)KP * 2;
    const char* gA = (const char*)Xb + (size_t)(m0 + 32 * wave + (lane >> 3)) * rowB + (lane & 7) * 16;
    const char* gB = (const char*)Wb + (size_t)(n0 + 32 * wave + (lane >> 3)) * rowB + (lane & 7) * 16;
    unsigned short* lA = &As[32 * wave][0];
    unsigned short* lB = &Bs[32 * wave][0];

    for (int kt = 0; kt < KP / 64; ++kt) {
        const size_t ko = (size_t)kt * 128;           // byte offset along K
#pragma unroll
        for (int s = 0; s < 4; ++s) {
            LDS_GLOAD16(gA + ko + (size_t)s * 8 * rowB, lA + s * 8 * 64);
            LDS_GLOAD16(gB + ko + (size_t)s * 8 * rowB, lB + s * 8 * 64);
        }
        __syncthreads();
#pragma unroll
        for (int ks = 0; ks < 2; ++ks) {
            bf16x8 a[4], b[4];
#pragma unroll
            for (int mi = 0; mi < 4; ++mi)
                a[mi] = *(const bf16x8*)&As[wr * 64 + mi * 16 + fr][ks * 32 + fq * 8];
#pragma unroll
            for (int nj = 0; nj < 4; ++nj)
                b[nj] = *(const bf16x8*)&Bs[wc * 64 + nj * 16 + fr][ks * 32 + fq * 8];
#pragma unroll
            for (int mi = 0; mi < 4; ++mi)
#pragma unroll
                for (int nj = 0; nj < 4; ++nj)
                    acc[mi][nj] = __builtin_amdgcn_mfma_f32_16x16x32_bf16(
                        a[mi], b[nj], acc[mi][nj], 0, 0, 0);
        }
        __syncthreads();
    }

    // C/D layout (m89-verified): col = lane&15, row = (lane>>4)*4 + reg
#pragma unroll
    for (int mi = 0; mi < 4; ++mi)
#pragma unroll
        for (int nj = 0; nj < 4; ++nj) {
            int r0 = m0 + wr * 64 + mi * 16 + fq * 4;
            int c  = n0 + wc * 64 + nj * 16 + fr;
#pragma unroll
            for (int r = 0; r < 4; ++r)
                Y[(size_t)(r0 + r) * H1 + c] = acc[mi][nj][r];
        }
}

// ---------------- fp32 fallback GEMM (used only if ws too small) ----------------
#define GBM 128
#define GBN 128
#define GBK 16
__global__ __launch_bounds__(256) void gemm_ff(const float* __restrict__ X,
                                               const float* __restrict__ W,
                                               float* __restrict__ Y) {
    const int K = NIN, N = H1;
    __shared__ float As[GBK][GBM + 4];
    __shared__ float Bs[GBK][GBN + 4];
    const int bn = blockIdx.x, bm = blockIdx.y;
    const int tid = threadIdx.x;
    const int tx = tid & 15, ty = tid >> 4;
    const int m0 = bm * GBM, n0 = bn * GBN;
    float acc[8][8] = {};
    for (int k0 = 0; k0 < K; k0 += GBK) {
#pragma unroll
        for (int l = 0; l < 8; ++l) {
            int idx = l * 256 + tid;
            int kk = idx & 15, r = idx >> 4;
            int kg = k0 + kk;
            As[kk][r] = (kg < K) ? X[(size_t)(m0 + r) * K + kg] : 0.f;
        }
#pragma unroll
        for (int l = 0; l < 8; ++l) {
            int idx = l * 256 + tid;
            int kk = idx & 15, r = idx >> 4;
            int kg = k0 + kk;
            Bs[kk][r] = (kg < K) ? W[(size_t)(n0 + r) * K + kg] : 0.f;
        }
        __syncthreads();
#pragma unroll
        for (int kk = 0; kk < GBK; ++kk) {
            float a[8], b[8];
#pragma unroll
            for (int i = 0; i < 8; ++i) a[i] = As[kk][ty * 8 + i];
#pragma unroll
            for (int j = 0; j < 8; ++j) b[j] = Bs[kk][tx * 8 + j];
#pragma unroll
            for (int i = 0; i < 8; ++i)
#pragma unroll
                for (int j = 0; j < 8; ++j)
                    acc[i][j] = fmaf(a[i], b[j], acc[i][j]);
        }
        __syncthreads();
    }
#pragma unroll
    for (int i = 0; i < 8; ++i)
#pragma unroll
        for (int j = 0; j < 8; ++j)
            Y[(size_t)(m0 + ty * 8 + i) * N + n0 + tx * 8 + j] = acc[i][j];
}

// ---------------- persistent per-batch SNN scan (v2) ----------------
// One block per batch element, 512 threads.
// - 2-deep register prefetch of I1ff rows (HBM latency off critical path)
// - 2 barriers/step: readout (phase 3) lags one step, runs on waves 4-5
//   concurrently with layer-2 (phase 2) on waves 0-3, via Bal2 double buffer.
__global__ __launch_bounds__(512) void snn_scan(
    const float* __restrict__ I1ff,   // [B][T][H1]
    const float* __restrict__ wrt,    // [H1][H1]  wrt[i][h] = w_rec[h][i]
    const float* __restrict__ w2t,    // [H1][H2]
    const float* __restrict__ w3t,    // [H2][NOUT]
    const float* __restrict__ alpha1, const float* __restrict__ rho1,
    const float* __restrict__ beta_a1,
    const float* __restrict__ alpha2, const float* __restrict__ rho2,
    const float* __restrict__ beta_a2,
    const float* __restrict__ beta_out,
    float* __restrict__ out)          // [B][NOUT]
{
    const int b = blockIdx.x;
    const int h = threadIdx.x;
    const int wave = h >> 6, lane = h & 63;

    __shared__ unsigned long long Bal1[8];     // layer-1 spikes (512 bits)
    __shared__ unsigned long long Bal2[2][4];  // layer-2 spikes, double-buffered

    // layer-1 state (all threads)
    float v1 = 0.f, a1 = 0.f, s1 = 0.f;
    const float al1 = alpha1[h], rh1 = rho1[h], ba1 = beta_a1[h];

    // layer-2 state (threads 0..255)
    float v2 = 0.f, a2 = 0.f, s2 = 0.f;
    float al2 = 0.f, rh2 = 0.f, ba2 = 0.f;
    if (h < H2) { al2 = alpha2[h]; rh2 = rho2[h]; ba2 = beta_a2[h]; }

    // readout state (threads 256..256+NOUT-1)
    const int o = h - 256;
    float vo = 0.f, vsum = 0.f, bo = 0.f;
    const bool is_out = (o >= 0) && (o < NOUT);
    if (is_out) bo = beta_out[o];

    if (h < 8) Bal1[h] = 0ull;
    if (h < 4) { Bal2[0][h] = 0ull; Bal2[1][h] = 0ull; }
    __syncthreads();

    const float* I1p = I1ff + (size_t)b * T_ * H1;

    auto step = [&](int t, float I1v) {
        // ---- phase 1: layer-1 adaptive LIF (all 512 threads) ----
        float rec = 0.f;
#pragma unroll
        for (int w = 0; w < 8; ++w) {
            unsigned long long bits = Bal1[w];
            while (bits) {
                int i = (w << 6) + __builtin_ctzll(bits);
                bits &= bits - 1;
                rec += wrt[i * H1 + h];
            }
        }
        float I1 = I1v + rec;
        float v1n = al1 * v1 + (1.f - al1) * (I1 - a1);
        float sp1 = (v1n > 1.f) ? 1.f : 0.f;
        v1 = v1n - sp1;
        a1 = rh1 * a1 + ba1 * s1;      // adaptation uses PREVIOUS spike
        s1 = sp1;

        __syncthreads();               // A: all reads of Bal1/Bal2 done
        unsigned long long m1 = __ballot(sp1 > 0.f);
        if (lane == 0) Bal1[wave] = m1;
        __syncthreads();               // B: new Bal1 visible

        // ---- phase 2 (waves 0-3) ∥ phase 3 for step t-1 (waves 4-5) ----
        if (h < H2) {
            float I2 = 0.f;
#pragma unroll
            for (int w = 0; w < 8; ++w) {
                unsigned long long bits = Bal1[w];
                while (bits) {
                    int i = (w << 6) + __builtin_ctzll(bits);
                    bits &= bits - 1;
                    I2 += w2t[i * H2 + h];
                }
            }
            float v2n = al2 * v2 + (1.f - al2) * (I2 - a2);
            float sp2 = (v2n > 1.f) ? 1.f : 0.f;
            v2 = v2n - sp2;
            a2 = rh2 * a2 + ba2 * s2;
            s2 = sp2;
            unsigned long long m2 = __ballot(sp2 > 0.f);
            if (lane == 0) Bal2[t & 1][wave] = m2;
        } else if (is_out && t > 0) {
            float io = 0.f;
            const int rb = (t & 1) ^ 1;   // previous step's buffer
#pragma unroll
            for (int w = 0; w < 4; ++w) {
                unsigned long long bits = Bal2[rb][w];
                while (bits) {
                    int i = (w << 6) + __builtin_ctzll(bits);
                    bits &= bits - 1;
                    io += w3t[i * NOUT + o];
                }
            }
            vo = bo * vo + (1.f - bo) * io;
            vsum += vo;
        }
        // no trailing barrier: next step's barrier A orders everything.
    };

    // 2-deep prefetch, time loop unrolled by 2 (T_=300 is even)
    float iA = I1p[h];
    float iB = I1p[H1 + h];
    for (int t = 0; t < T_; t += 2) {
        float useA = iA;
        { int tp = (t + 2 < T_) ? t + 2 : T_ - 1; iA = I1p[(size_t)tp * H1 + h]; }
        step(t, useA);
        float useB = iB;
        { int tp = (t + 3 < T_) ? t + 3 : T_ - 1; iB = I1p[(size_t)tp * H1 + h]; }
        step(t + 1, useB);
    }

    // epilogue: readout for t = T_-1
    __syncthreads();                   // make last Bal2 write visible
    if (is_out) {
        float io = 0.f;
        const int rb = (T_ - 1) & 1;
#pragma unroll
        for (int w = 0; w < 4; ++w) {
            unsigned long long bits = Bal2[rb][w];
            while (bits) {
                int i = (w << 6) + __builtin_ctzll(bits);
                bits &= bits - 1;
                io += w3t[i * NOUT + o];
            }
        }
        vo = bo * vo + (1.f - bo) * io;
        vsum += vo;
        out[b * NOUT + o] = vsum * (1.f / (float)T_);
    }
}

// ---------------- launch ----------------
extern "C" void kernel_launch(void* const* d_in, const int* in_sizes, int n_in,
                              void* d_out, int out_size, void* d_ws, size_t ws_size,
                              hipStream_t stream) {
    const float* x      = (const float*)d_in[0];   // [B][T][NIN]
    const float* w1     = (const float*)d_in[1];   // [H1][NIN]
    const float* w_rec  = (const float*)d_in[2];   // [H1][H1]
    const float* w2     = (const float*)d_in[3];   // [H2][H1]
    const float* w3     = (const float*)d_in[4];   // [NOUT][H2]
    const float* alpha1 = (const float*)d_in[5];
    const float* rho1   = (const float*)d_in[6];
    const float* beta_a1= (const float*)d_in[7];
    const float* alpha2 = (const float*)d_in[8];
    const float* rho2   = (const float*)d_in[9];
    const float* beta_a2= (const float*)d_in[10];
    const float* beta_out=(const float*)d_in[11];
    float* out = (float*)d_out;

    const int M = B_ * T_;                         // 19200

    size_t off = 0;
    auto take = [&](size_t bytes) {
        void* p = (char*)d_ws + off;
        off += (bytes + 255) & ~(size_t)255;
        return p;
    };
    float* I1ff = (float*)take((size_t)M * H1 * 4);            // 39.3 MB
    float* wrt  = (float*)take((size_t)H1 * H1 * 4);
    float* w2t  = (float*)take((size_t)H1 * H2 * 4);
    float* w3t  = (float*)take((size_t)H2 * NOUT * 4);
    unsigned short* xb  = (unsigned short*)take((size_t)M * KP * 2);   // 90.9 MB
    unsigned short* w1b = (unsigned short*)take((size_t)H1 * KP * 2);  // 2.4 MB
    bool use_bf16 = (off <= ws_size);

    transpose_k<<<(H1 * H1 + 255) / 256, 256, 0, stream>>>(w_rec, wrt, H1, H1);
    transpose_k<<<(H2 * H1 + 255) / 256, 256, 0, stream>>>(w2, w2t, H2, H1);
    transpose_k<<<(NOUT * H2 + 255) / 256, 256, 0, stream>>>(w3, w3t, NOUT, H2);

    if (use_bf16) {
        int nx = M * (KP / 8);
        cvt_pad_bf16<<<(nx + 255) / 256, 256, 0, stream>>>(x, xb, M, NIN, KP);
        int nw = H1 * (KP / 8);
        cvt_pad_bf16<<<(nw + 255) / 256, 256, 0, stream>>>(w1, w1b, H1, NIN, KP);

        dim3 gg(H1 / 128, M / 128);   // (4, 150)
        gemm_bf16<<<gg, 256, 0, stream>>>(xb, w1b, I1ff);
    } else {
        dim3 gg(H1 / GBN, M / GBM);
        gemm_ff<<<gg, 256, 0, stream>>>(x, w1, I1ff);
    }

    snn_scan<<<B_, 512, 0, stream>>>(I1ff, wrt, w2t, w3t,
                                     alpha1, rho1, beta_a1,
                                     alpha2, rho2, beta_a2,
                                     beta_out, out);
}

// Round 4
// 352.498 us; speedup vs baseline: 4.5372x; 1.3937x over previous
//
#include <hip/hip_runtime.h>
#include <hip/hip_bf16.h>
#include <stdint.h>

// Problem constants
#define B_   64
#define T_   300
#define NIN  2312
#define H1   512
#define H2   256
#define NOUT 101
#define KP   2368   // NIN padded up to a multiple of 64 (2368 = 37*64)

typedef __attribute__((ext_vector_type(8))) short bf16x8;
typedef __attribute__((ext_vector_type(4))) float f32x4;
typedef __attribute__((ext_vector_type(8))) unsigned short u16x8;

// ---------------- transpose helper (tiny, perf-irrelevant) ----------------
__global__ void transpose_k(const float* __restrict__ src, float* __restrict__ dst,
                            int R, int C) {
    int idx = blockIdx.x * 256 + threadIdx.x;
    if (idx < R * C) {
        int r = idx / C, c = idx % C;
        dst[c * R + r] = src[r * C + c];
    }
}

// ---------------- fp32 -> bf16 (RNE) with K-padding, float4 loads ----------------
__device__ __forceinline__ unsigned short rne_bf16(float v) {
    union { float f; unsigned u; } cv; cv.f = v;
    return (unsigned short)((cv.u + 0x7fff + ((cv.u >> 16) & 1)) >> 16);
}

__global__ __launch_bounds__(256) void cvt_pad_bf16(const float* __restrict__ src,
                                                    unsigned short* __restrict__ dst,
                                                    int R, int C, int Cp) {
    int idx = blockIdx.x * 256 + threadIdx.x;
    int cpw = Cp >> 3;
    if (idx >= R * cpw) return;
    int row = idx / cpw;
    int c0 = (idx - row * cpw) << 3;
    u16x8 o;
    if (c0 + 8 <= C) {
        const float4* s = (const float4*)(src + (size_t)row * C + c0);
        float4 v0 = s[0], v1 = s[1];
        float v[8] = {v0.x, v0.y, v0.z, v0.w, v1.x, v1.y, v1.z, v1.w};
#pragma unroll
        for (int j = 0; j < 8; ++j) o[j] = rne_bf16(v[j]);
    } else {
#pragma unroll
        for (int j = 0; j < 8; ++j) {
            int k = c0 + j;
            o[j] = (k < C) ? rne_bf16(src[(size_t)row * C + k]) : (unsigned short)0;
        }
    }
    *(u16x8*)(dst + (size_t)row * Cp + c0) = o;
}

// ---------------- bf16 MFMA GEMM (m97 structure + XCD swizzle) ----------------
#define LDS_GLOAD16(g, l) \
  __builtin_amdgcn_global_load_lds((const __attribute__((address_space(1))) void*)(g), \
                                   (__attribute__((address_space(3))) void*)(l), 16, 0, 0)

__global__ __launch_bounds__(256) void gemm_bf16(
    const unsigned short* __restrict__ Xb,   // [M][KP] bf16 bits
    const unsigned short* __restrict__ Wb,   // [H1][KP] bf16 bits
    float* __restrict__ Y)                   // [M][H1]
{
    __shared__ __align__(16) unsigned short As[128][64];
    __shared__ __align__(16) unsigned short Bs[128][64];

    const int tid  = threadIdx.x;
    const int wave = tid >> 6, lane = tid & 63;
    const int wr = wave >> 1, wc = wave & 1;          // 2x2 waves, 64x64 each

    // XCD-bijective swizzle: grid (4,150) = 600 blocks, 600 % 8 == 0.
    // Consecutive logical m-panels land on the same XCD -> A-panel L2 reuse x4.
    const int d  = blockIdx.x + gridDim.x * blockIdx.y;   // 0..599
    const int wg = (d & 7) * 75 + (d >> 3);
    const int bn = wg & 3, bm = wg >> 2;
    const int m0 = bm * 128, n0 = bn * 128;
    const int fr = lane & 15, fq = lane >> 4;

    f32x4 acc[4][4] = {};

    const size_t rowB = (size_t)KP * 2;
    const char* gA = (const char*)Xb + (size_t)(m0 + 32 * wave + (lane >> 3)) * rowB + (lane & 7) * 16;
    const char* gB = (const char*)Wb + (size_t)(n0 + 32 * wave + (lane >> 3)) * rowB + (lane & 7) * 16;
    unsigned short* lA = &As[32 * wave][0];
    unsigned short* lB = &Bs[32 * wave][0];

    for (int kt = 0; kt < KP / 64; ++kt) {
        const size_t ko = (size_t)kt * 128;           // byte offset along K
#pragma unroll
        for (int s = 0; s < 4; ++s) {
            LDS_GLOAD16(gA + ko + (size_t)s * 8 * rowB, lA + s * 8 * 64);
            LDS_GLOAD16(gB + ko + (size_t)s * 8 * rowB, lB + s * 8 * 64);
        }
        __syncthreads();
#pragma unroll
        for (int ks = 0; ks < 2; ++ks) {
            bf16x8 a[4], b[4];
#pragma unroll
            for (int mi = 0; mi < 4; ++mi)
                a[mi] = *(const bf16x8*)&As[wr * 64 + mi * 16 + fr][ks * 32 + fq * 8];
#pragma unroll
            for (int nj = 0; nj < 4; ++nj)
                b[nj] = *(const bf16x8*)&Bs[wc * 64 + nj * 16 + fr][ks * 32 + fq * 8];
#pragma unroll
            for (int mi = 0; mi < 4; ++mi)
#pragma unroll
                for (int nj = 0; nj < 4; ++nj)
                    acc[mi][nj] = __builtin_amdgcn_mfma_f32_16x16x32_bf16(
                        a[mi], b[nj], acc[mi][nj], 0, 0, 0);
        }
        __syncthreads();
    }

    // C/D layout (m89-verified): col = lane&15, row = (lane>>4)*4 + reg
#pragma unroll
    for (int mi = 0; mi < 4; ++mi)
#pragma unroll
        for (int nj = 0; nj < 4; ++nj) {
            int r0 = m0 + wr * 64 + mi * 16 + fq * 4;
            int c  = n0 + wc * 64 + nj * 16 + fr;
#pragma unroll
            for (int r = 0; r < 4; ++r)
                Y[(size_t)(r0 + r) * H1 + c] = acc[mi][nj][r];
        }
}

// ---------------- fp32 fallback GEMM (used only if ws too small) ----------------
#define GBM 128
#define GBN 128
#define GBK 16
__global__ __launch_bounds__(256) void gemm_ff(const float* __restrict__ X,
                                               const float* __restrict__ W,
                                               float* __restrict__ Y) {
    const int K = NIN, N = H1;
    __shared__ float As[GBK][GBM + 4];
    __shared__ float Bs[GBK][GBN + 4];
    const int bn = blockIdx.x, bm = blockIdx.y;
    const int tid = threadIdx.x;
    const int tx = tid & 15, ty = tid >> 4;
    const int m0 = bm * GBM, n0 = bn * GBN;
    float acc[8][8] = {};
    for (int k0 = 0; k0 < K; k0 += GBK) {
#pragma unroll
        for (int l = 0; l < 8; ++l) {
            int idx = l * 256 + tid;
            int kk = idx & 15, r = idx >> 4;
            int kg = k0 + kk;
            As[kk][r] = (kg < K) ? X[(size_t)(m0 + r) * K + kg] : 0.f;
        }
#pragma unroll
        for (int l = 0; l < 8; ++l) {
            int idx = l * 256 + tid;
            int kk = idx & 15, r = idx >> 4;
            int kg = k0 + kk;
            Bs[kk][r] = (kg < K) ? W[(size_t)(n0 + r) * K + kg] : 0.f;
        }
        __syncthreads();
#pragma unroll
        for (int kk = 0; kk < GBK; ++kk) {
            float a[8], b[8];
#pragma unroll
            for (int i = 0; i < 8; ++i) a[i] = As[kk][ty * 8 + i];
#pragma unroll
            for (int j = 0; j < 8; ++j) b[j] = Bs[kk][tx * 8 + j];
#pragma unroll
            for (int i = 0; i < 8; ++i)
#pragma unroll
                for (int j = 0; j < 8; ++j)
                    acc[i][j] = fmaf(a[i], b[j], acc[i][j]);
        }
        __syncthreads();
    }
#pragma unroll
    for (int i = 0; i < 8; ++i)
#pragma unroll
        for (int j = 0; j < 8; ++j)
            Y[(size_t)(m0 + ty * 8 + i) * N + n0 + tx * 8 + j] = acc[i][j];
}

// ---------------- wave-per-batch SNN scan (v3): barrier-free ----------------
// One 64-lane wave per batch element. Lane owns 8 L1 neurons (h=lane+64j),
// 4 L2 neurons, up to 2 outputs. Spike masks via __ballot only — no LDS,
// no __syncthreads on the 300-step critical path.
__global__ __launch_bounds__(64) void snn_scan_wave(
    const float* __restrict__ I1ff,   // [B][T][H1]
    const float* __restrict__ wrt,    // [H1][H1]  wrt[i][h] = w_rec[h][i]
    const float* __restrict__ w2t,    // [H1][H2]  w2t[i][j] = w2[j][i]
    const float* __restrict__ w3t,    // [H2][NOUT]
    const float* __restrict__ alpha1, const float* __restrict__ rho1,
    const float* __restrict__ beta_a1,
    const float* __restrict__ alpha2, const float* __restrict__ rho2,
    const float* __restrict__ beta_a2,
    const float* __restrict__ beta_out,
    float* __restrict__ out)          // [B][NOUT]
{
    const int b = blockIdx.x;
    const int lane = threadIdx.x;     // 0..63

    // layer-1 per-lane state (8 neurons)
    float v1[8], a1[8], al1[8], oml1[8], rh1[8], ba1[8];
#pragma unroll
    for (int j = 0; j < 8; ++j) {
        int h = lane + 64 * j;
        v1[j] = 0.f; a1[j] = 0.f;
        al1[j] = alpha1[h]; oml1[j] = 1.f - al1[j];
        rh1[j] = rho1[h];   ba1[j] = beta_a1[h];
    }
    unsigned sp1 = 0;   // bit j = previous spike of neuron lane+64j

    // layer-2 per-lane state (4 neurons)
    float v2[4], a2[4], al2[4], oml2[4], rh2[4], ba2[4];
#pragma unroll
    for (int j = 0; j < 4; ++j) {
        int h = lane + 64 * j;
        v2[j] = 0.f; a2[j] = 0.f;
        al2[j] = alpha2[h]; oml2[j] = 1.f - al2[j];
        rh2[j] = rho2[h];   ba2[j] = beta_a2[h];
    }
    unsigned sp2 = 0;

    // readout (o = lane, o = 64+lane if lane<37)
    float vo0 = 0.f, vo1 = 0.f, vs0 = 0.f, vs1 = 0.f;
    float bo0 = beta_out[lane];
    float bo1 = (lane < NOUT - 64) ? beta_out[64 + lane] : 0.f;

    unsigned long long M1[8];
#pragma unroll
    for (int j = 0; j < 8; ++j) M1[j] = 0ull;

    const float* I1p = I1ff + (size_t)b * T_ * H1;
    float iA[8], iB[8];
#pragma unroll
    for (int j = 0; j < 8; ++j) iA[j] = I1p[lane + 64 * j];
#pragma unroll
    for (int j = 0; j < 8; ++j) iB[j] = I1p[H1 + lane + 64 * j];

    for (int t = 0; t < T_; ++t) {
        // rotate prefetch buffers; issue load for t+2 (clamped)
        float cur[8];
#pragma unroll
        for (int j = 0; j < 8; ++j) { cur[j] = iA[j]; iA[j] = iB[j]; }
        {
            int tp = (t + 2 < T_) ? t + 2 : T_ - 1;
            const float* pre = I1p + (size_t)tp * H1;
#pragma unroll
            for (int j = 0; j < 8; ++j) iB[j] = pre[lane + 64 * j];
        }

        // ---- layer 1: recurrent gather over PREVIOUS spikes (M1) ----
        float rec[8];
#pragma unroll
        for (int j = 0; j < 8; ++j) rec[j] = 0.f;
#pragma unroll
        for (int w = 0; w < 8; ++w) {
            unsigned long long bits = M1[w];
            while (bits) {
                int i = (w << 6) + __builtin_ctzll(bits);
                bits &= bits - 1;
                const float* r = wrt + (size_t)i * H1 + lane;
#pragma unroll
                for (int j = 0; j < 8; ++j) rec[j] += r[64 * j];
            }
        }

        unsigned ns = 0;
#pragma unroll
        for (int j = 0; j < 8; ++j) {
            float I1  = cur[j] + rec[j];
            float v1n = al1[j] * v1[j] + oml1[j] * (I1 - a1[j]);
            float sp  = (v1n > 1.f) ? 1.f : 0.f;
            v1[j] = v1n - sp;                                  // soft reset
            a1[j] = rh1[j] * a1[j] + ba1[j] * (float)((sp1 >> j) & 1);
            ns |= ((v1n > 1.f) ? 1u : 0u) << j;
        }
        sp1 = ns;
#pragma unroll
        for (int j = 0; j < 8; ++j) M1[j] = __ballot((ns >> j) & 1);

        // ---- layer 2: gather over NEW layer-1 spikes ----
        float I2[4];
#pragma unroll
        for (int j = 0; j < 4; ++j) I2[j] = 0.f;
#pragma unroll
        for (int w = 0; w < 8; ++w) {
            unsigned long long bits = M1[w];
            while (bits) {
                int i = (w << 6) + __builtin_ctzll(bits);
                bits &= bits - 1;
                const float* r = w2t + (size_t)i * H2 + lane;
#pragma unroll
                for (int j = 0; j < 4; ++j) I2[j] += r[64 * j];
            }
        }
        unsigned ns2 = 0;
#pragma unroll
        for (int j = 0; j < 4; ++j) {
            float v2n = al2[j] * v2[j] + oml2[j] * (I2[j] - a2[j]);
            float sp  = (v2n > 1.f) ? 1.f : 0.f;
            v2[j] = v2n - sp;
            a2[j] = rh2[j] * a2[j] + ba2[j] * (float)((sp2 >> j) & 1);
            ns2 |= ((v2n > 1.f) ? 1u : 0u) << j;
        }
        sp2 = ns2;
        unsigned long long M2[4];
#pragma unroll
        for (int j = 0; j < 4; ++j) M2[j] = __ballot((ns2 >> j) & 1);

        // ---- readout over NEW layer-2 spikes ----
        float io0 = 0.f, io1 = 0.f;
#pragma unroll
        for (int w = 0; w < 4; ++w) {
            unsigned long long bits = M2[w];
            while (bits) {
                int i = (w << 6) + __builtin_ctzll(bits);
                bits &= bits - 1;
                io0 += w3t[(size_t)i * NOUT + lane];
                if (lane < NOUT - 64) io1 += w3t[(size_t)i * NOUT + 64 + lane];
            }
        }
        vo0 = bo0 * vo0 + (1.f - bo0) * io0;
        vo1 = bo1 * vo1 + (1.f - bo1) * io1;
        vs0 += vo0;
        vs1 += vo1;
    }

    out[b * NOUT + lane] = vs0 * (1.f / (float)T_);
    if (lane < NOUT - 64) out[b * NOUT + 64 + lane] = vs1 * (1.f / (float)T_);
}

// ---------------- launch ----------------
extern "C" void kernel_launch(void* const* d_in, const int* in_sizes, int n_in,
                              void* d_out, int out_size, void* d_ws, size_t ws_size,
                              hipStream_t stream) {
    const float* x      = (const float*)d_in[0];   // [B][T][NIN]
    const float* w1     = (const float*)d_in[1];   // [H1][NIN]
    const float* w_rec  = (const float*)d_in[2];   // [H1][H1]
    const float* w2     = (const float*)d_in[3];   // [H2][H1]
    const float* w3     = (const float*)d_in[4];   // [NOUT][H2]
    const float* alpha1 = (const float*)d_in[5];
    const float* rho1   = (const float*)d_in[6];
    const float* beta_a1= (const float*)d_in[7];
    const float* alpha2 = (const float*)d_in[8];
    const float* rho2   = (const float*)d_in[9];
    const float* beta_a2= (const float*)d_in[10];
    const float* beta_out=(const float*)d_in[11];
    float* out = (float*)d_out;

    const int M = B_ * T_;                         // 19200

    size_t off = 0;
    auto take = [&](size_t bytes) {
        void* p = (char*)d_ws + off;
        off += (bytes + 255) & ~(size_t)255;
        return p;
    };
    float* I1ff = (float*)take((size_t)M * H1 * 4);            // 39.3 MB
    float* wrt  = (float*)take((size_t)H1 * H1 * 4);
    float* w2t  = (float*)take((size_t)H1 * H2 * 4);
    float* w3t  = (float*)take((size_t)H2 * NOUT * 4);
    unsigned short* xb  = (unsigned short*)take((size_t)M * KP * 2);   // 90.9 MB
    unsigned short* w1b = (unsigned short*)take((size_t)H1 * KP * 2);  // 2.4 MB
    bool use_bf16 = (off <= ws_size);

    transpose_k<<<(H1 * H1 + 255) / 256, 256, 0, stream>>>(w_rec, wrt, H1, H1);
    transpose_k<<<(H2 * H1 + 255) / 256, 256, 0, stream>>>(w2, w2t, H2, H1);
    transpose_k<<<(NOUT * H2 + 255) / 256, 256, 0, stream>>>(w3, w3t, NOUT, H2);

    if (use_bf16) {
        int nx = M * (KP / 8);
        cvt_pad_bf16<<<(nx + 255) / 256, 256, 0, stream>>>(x, xb, M, NIN, KP);
        int nw = H1 * (KP / 8);
        cvt_pad_bf16<<<(nw + 255) / 256, 256, 0, stream>>>(w1, w1b, H1, NIN, KP);

        dim3 gg(H1 / 128, M / 128);   // (4, 150) = 600 blocks (swizzle assumes 600)
        gemm_bf16<<<gg, 256, 0, stream>>>(xb, w1b, I1ff);
    } else {
        dim3 gg(H1 / GBN, M / GBM);
        gemm_ff<<<gg, 256, 0, stream>>>(x, w1, I1ff);
    }

    snn_scan_wave<<<B_, 64, 0, stream>>>(I1ff, wrt, w2t, w3t,
                                         alpha1, rho1, beta_a1,
                                         alpha2, rho2, beta_a2,
                                         beta_out, out);
}

// Round 5
// 329.869 us; speedup vs baseline: 4.8484x; 1.0686x over previous
//
#include <hip/hip_runtime.h>
#include <hip/hip_bf16.h>
#include <stdint.h>

// Problem constants
#define B_   64
#define T_   300
#define NIN  2312
#define H1   512
#define H2   256
#define NOUT 101
#define KP   2368   // NIN padded up to a multiple of 64 (2368 = 37*64)
#define CH   15     // I1 staging chunk (timesteps); 300 = 20*15; 2*15*2KB = 60KB LDS

typedef __attribute__((ext_vector_type(8))) short bf16x8;
typedef __attribute__((ext_vector_type(4))) float f32x4;
typedef __attribute__((ext_vector_type(8))) unsigned short u16x8;

#define LDS_GLOAD16(g, l) \
  __builtin_amdgcn_global_load_lds((const __attribute__((address_space(1))) void*)(g), \
                                   (__attribute__((address_space(3))) void*)(l), 16, 0, 0)

// ---------------- transpose helper (tiny, perf-irrelevant) ----------------
__global__ void transpose_k(const float* __restrict__ src, float* __restrict__ dst,
                            int R, int C) {
    int idx = blockIdx.x * 256 + threadIdx.x;
    if (idx < R * C) {
        int r = idx / C, c = idx % C;
        dst[c * R + r] = src[r * C + c];
    }
}

// ---------------- fp32 -> bf16 (RNE) with K-padding, float4 loads ----------------
__device__ __forceinline__ unsigned short rne_bf16(float v) {
    union { float f; unsigned u; } cv; cv.f = v;
    return (unsigned short)((cv.u + 0x7fff + ((cv.u >> 16) & 1)) >> 16);
}

__global__ __launch_bounds__(256) void cvt_pad_bf16(const float* __restrict__ src,
                                                    unsigned short* __restrict__ dst,
                                                    int R, int C, int Cp) {
    int idx = blockIdx.x * 256 + threadIdx.x;
    int cpw = Cp >> 3;
    if (idx >= R * cpw) return;
    int row = idx / cpw;
    int c0 = (idx - row * cpw) << 3;
    u16x8 o;
    if (c0 + 8 <= C) {
        const float4* s = (const float4*)(src + (size_t)row * C + c0);
        float4 v0 = s[0], v1 = s[1];
        float v[8] = {v0.x, v0.y, v0.z, v0.w, v1.x, v1.y, v1.z, v1.w};
#pragma unroll
        for (int j = 0; j < 8; ++j) o[j] = rne_bf16(v[j]);
    } else {
#pragma unroll
        for (int j = 0; j < 8; ++j) {
            int k = c0 + j;
            o[j] = (k < C) ? rne_bf16(src[(size_t)row * C + k]) : (unsigned short)0;
        }
    }
    *(u16x8*)(dst + (size_t)row * Cp + c0) = o;
}

// ---------------- bf16 MFMA GEMM (m97 structure + XCD swizzle) ----------------
__global__ __launch_bounds__(256) void gemm_bf16(
    const unsigned short* __restrict__ Xb,   // [M][KP] bf16 bits
    const unsigned short* __restrict__ Wb,   // [H1][KP] bf16 bits
    float* __restrict__ Y)                   // [M][H1]
{
    __shared__ __align__(16) unsigned short As[128][64];
    __shared__ __align__(16) unsigned short Bs[128][64];

    const int tid  = threadIdx.x;
    const int wave = tid >> 6, lane = tid & 63;
    const int wr = wave >> 1, wc = wave & 1;          // 2x2 waves, 64x64 each

    // XCD-bijective swizzle: grid (4,150) = 600 blocks, 600 % 8 == 0.
    const int d  = blockIdx.x + gridDim.x * blockIdx.y;   // 0..599
    const int wg = (d & 7) * 75 + (d >> 3);
    const int bn = wg & 3, bm = wg >> 2;
    const int m0 = bm * 128, n0 = bn * 128;
    const int fr = lane & 15, fq = lane >> 4;

    f32x4 acc[4][4] = {};

    const size_t rowB = (size_t)KP * 2;
    const char* gA = (const char*)Xb + (size_t)(m0 + 32 * wave + (lane >> 3)) * rowB + (lane & 7) * 16;
    const char* gB = (const char*)Wb + (size_t)(n0 + 32 * wave + (lane >> 3)) * rowB + (lane & 7) * 16;
    unsigned short* lA = &As[32 * wave][0];
    unsigned short* lB = &Bs[32 * wave][0];

    for (int kt = 0; kt < KP / 64; ++kt) {
        const size_t ko = (size_t)kt * 128;           // byte offset along K
#pragma unroll
        for (int s = 0; s < 4; ++s) {
            LDS_GLOAD16(gA + ko + (size_t)s * 8 * rowB, lA + s * 8 * 64);
            LDS_GLOAD16(gB + ko + (size_t)s * 8 * rowB, lB + s * 8 * 64);
        }
        __syncthreads();
#pragma unroll
        for (int ks = 0; ks < 2; ++ks) {
            bf16x8 a[4], b[4];
#pragma unroll
            for (int mi = 0; mi < 4; ++mi)
                a[mi] = *(const bf16x8*)&As[wr * 64 + mi * 16 + fr][ks * 32 + fq * 8];
#pragma unroll
            for (int nj = 0; nj < 4; ++nj)
                b[nj] = *(const bf16x8*)&Bs[wc * 64 + nj * 16 + fr][ks * 32 + fq * 8];
#pragma unroll
            for (int mi = 0; mi < 4; ++mi)
#pragma unroll
                for (int nj = 0; nj < 4; ++nj)
                    acc[mi][nj] = __builtin_amdgcn_mfma_f32_16x16x32_bf16(
                        a[mi], b[nj], acc[mi][nj], 0, 0, 0);
        }
        __syncthreads();
    }

    // C/D layout (m89-verified): col = lane&15, row = (lane>>4)*4 + reg
#pragma unroll
    for (int mi = 0; mi < 4; ++mi)
#pragma unroll
        for (int nj = 0; nj < 4; ++nj) {
            int r0 = m0 + wr * 64 + mi * 16 + fq * 4;
            int c  = n0 + wc * 64 + nj * 16 + fr;
#pragma unroll
            for (int r = 0; r < 4; ++r)
                Y[(size_t)(r0 + r) * H1 + c] = acc[mi][nj][r];
        }
}

// ---------------- fp32 fallback GEMM (used only if ws too small) ----------------
#define GBM 128
#define GBN 128
#define GBK 16
__global__ __launch_bounds__(256) void gemm_ff(const float* __restrict__ X,
                                               const float* __restrict__ W,
                                               float* __restrict__ Y) {
    const int K = NIN, N = H1;
    __shared__ float As[GBK][GBM + 4];
    __shared__ float Bs[GBK][GBN + 4];
    const int bn = blockIdx.x, bm = blockIdx.y;
    const int tid = threadIdx.x;
    const int tx = tid & 15, ty = tid >> 4;
    const int m0 = bm * GBM, n0 = bn * GBN;
    float acc[8][8] = {};
    for (int k0 = 0; k0 < K; k0 += GBK) {
#pragma unroll
        for (int l = 0; l < 8; ++l) {
            int idx = l * 256 + tid;
            int kk = idx & 15, r = idx >> 4;
            int kg = k0 + kk;
            As[kk][r] = (kg < K) ? X[(size_t)(m0 + r) * K + kg] : 0.f;
        }
#pragma unroll
        for (int l = 0; l < 8; ++l) {
            int idx = l * 256 + tid;
            int kk = idx & 15, r = idx >> 4;
            int kg = k0 + kk;
            Bs[kk][r] = (kg < K) ? W[(size_t)(n0 + r) * K + kg] : 0.f;
        }
        __syncthreads();
#pragma unroll
        for (int kk = 0; kk < GBK; ++kk) {
            float a[8], b[8];
#pragma unroll
            for (int i = 0; i < 8; ++i) a[i] = As[kk][ty * 8 + i];
#pragma unroll
            for (int j = 0; j < 8; ++j) b[j] = Bs[kk][tx * 8 + j];
#pragma unroll
            for (int i = 0; i < 8; ++i)
#pragma unroll
                for (int j = 0; j < 8; ++j)
                    acc[i][j] = fmaf(a[i], b[j], acc[i][j]);
        }
        __syncthreads();
    }
#pragma unroll
    for (int i = 0; i < 8; ++i)
#pragma unroll
        for (int j = 0; j < 8; ++j)
            Y[(size_t)(m0 + ty * 8 + i) * N + n0 + tx * 8 + j] = acc[i][j];
}

// ---------------- wave-per-batch SNN scan (v4): barrier-free + LDS I1 chunks ----
// One 64-lane wave per batch element. I1 is staged CH timesteps at a time into
// double-buffered LDS via global_load_lds, so per-step I1 reads are ds_read
// (lgkmcnt) and the vmcnt FIFO drain is paid once per CH steps, not per step.
__global__ __launch_bounds__(64) void snn_scan_wave(
    const float* __restrict__ I1ff,   // [B][T][H1]
    const float* __restrict__ wrt,    // [H1][H1]  wrt[i][h] = w_rec[h][i]
    const float* __restrict__ w2t,    // [H1][H2]  w2t[i][j] = w2[j][i]
    const float* __restrict__ w3t,    // [H2][NOUT]
    const float* __restrict__ alpha1, const float* __restrict__ rho1,
    const float* __restrict__ beta_a1,
    const float* __restrict__ alpha2, const float* __restrict__ rho2,
    const float* __restrict__ beta_a2,
    const float* __restrict__ beta_out,
    float* __restrict__ out)          // [B][NOUT]
{
    __shared__ __align__(16) float Ich[2][CH][H1];   // 60 KB

    const int b = blockIdx.x;
    const int lane = threadIdx.x;     // 0..63

    // layer-1 per-lane state (8 neurons, h = lane + 64j)
    float v1[8], a1[8], al1[8], oml1[8], rh1[8], ba1[8];
#pragma unroll
    for (int j = 0; j < 8; ++j) {
        int h = lane + 64 * j;
        v1[j] = 0.f; a1[j] = 0.f;
        al1[j] = alpha1[h]; oml1[j] = 1.f - al1[j];
        rh1[j] = rho1[h];   ba1[j] = beta_a1[h];
    }
    unsigned sp1 = 0;

    // layer-2 per-lane state (4 neurons)
    float v2[4], a2[4], al2[4], oml2[4], rh2[4], ba2[4];
#pragma unroll
    for (int j = 0; j < 4; ++j) {
        int h = lane + 64 * j;
        v2[j] = 0.f; a2[j] = 0.f;
        al2[j] = alpha2[h]; oml2[j] = 1.f - al2[j];
        rh2[j] = rho2[h];   ba2[j] = beta_a2[h];
    }
    unsigned sp2 = 0;

    // readout (o = lane; o = 64+lane if lane < NOUT-64)
    float vo0 = 0.f, vo1 = 0.f, vs0 = 0.f, vs1 = 0.f;
    float bo0 = beta_out[lane];
    float bo1 = (lane < NOUT - 64) ? beta_out[64 + lane] : 0.f;

    unsigned long long M1[8];
#pragma unroll
    for (int j = 0; j < 8; ++j) M1[j] = 0ull;

    const float* I1p = I1ff + (size_t)b * T_ * H1;

    // stage one chunk (CH rows of 512 floats): 2 x 1KB loads per row
    auto stage = [&](int c, int buf) {
        const float* src = I1p + (size_t)c * CH * H1 + lane * 4;
#pragma unroll
        for (int s = 0; s < CH; ++s) {
            LDS_GLOAD16(src + (size_t)s * H1,       &Ich[buf][s][0]);
            LDS_GLOAD16(src + (size_t)s * H1 + 256, &Ich[buf][s][256]);
        }
    };

    stage(0, 0);

    for (int c = 0; c < T_ / CH; ++c) {
        const int buf = c & 1;
        asm volatile("s_waitcnt vmcnt(0)" ::: "memory");   // chunk c resident
        if (c + 1 < T_ / CH) stage(c + 1, buf ^ 1);

        for (int s = 0; s < CH; ++s) {
            // ---- I1 from LDS (lgkmcnt path — off the vmem FIFO) ----
            float cur[8];
#pragma unroll
            for (int j = 0; j < 8; ++j) cur[j] = Ich[buf][s][lane + 64 * j];

            // ---- layer 1: recurrent gather over PREVIOUS spikes ----
            float rec[8];
#pragma unroll
            for (int j = 0; j < 8; ++j) rec[j] = 0.f;
#pragma unroll
            for (int w = 0; w < 8; ++w) {
                unsigned long long bits = M1[w];
                while (bits) {
                    int i = (w << 6) + __builtin_ctzll(bits);
                    bits &= bits - 1;
                    const float* r = wrt + (size_t)i * H1 + lane;
#pragma unroll
                    for (int j = 0; j < 8; ++j) rec[j] += r[64 * j];
                }
            }

            unsigned ns = 0;
#pragma unroll
            for (int j = 0; j < 8; ++j) {
                float I1  = cur[j] + rec[j];
                float v1n = al1[j] * v1[j] + oml1[j] * (I1 - a1[j]);
                float sp  = (v1n > 1.f) ? 1.f : 0.f;
                v1[j] = v1n - sp;                                  // soft reset
                a1[j] = rh1[j] * a1[j] + ba1[j] * (float)((sp1 >> j) & 1);
                ns |= ((v1n > 1.f) ? 1u : 0u) << j;
            }
            sp1 = ns;
#pragma unroll
            for (int j = 0; j < 8; ++j) M1[j] = __ballot((ns >> j) & 1);

            // ---- layer 2: gather over NEW layer-1 spikes ----
            float I2[4];
#pragma unroll
            for (int j = 0; j < 4; ++j) I2[j] = 0.f;
#pragma unroll
            for (int w = 0; w < 8; ++w) {
                unsigned long long bits = M1[w];
                while (bits) {
                    int i = (w << 6) + __builtin_ctzll(bits);
                    bits &= bits - 1;
                    const float* r = w2t + (size_t)i * H2 + lane;
#pragma unroll
                    for (int j = 0; j < 4; ++j) I2[j] += r[64 * j];
                }
            }
            unsigned ns2 = 0;
#pragma unroll
            for (int j = 0; j < 4; ++j) {
                float v2n = al2[j] * v2[j] + oml2[j] * (I2[j] - a2[j]);
                float sp  = (v2n > 1.f) ? 1.f : 0.f;
                v2[j] = v2n - sp;
                a2[j] = rh2[j] * a2[j] + ba2[j] * (float)((sp2 >> j) & 1);
                ns2 |= ((v2n > 1.f) ? 1u : 0u) << j;
            }
            sp2 = ns2;
            unsigned long long M2[4];
#pragma unroll
            for (int j = 0; j < 4; ++j) M2[j] = __ballot((ns2 >> j) & 1);

            // ---- readout over NEW layer-2 spikes ----
            float io0 = 0.f, io1 = 0.f;
#pragma unroll
            for (int w = 0; w < 4; ++w) {
                unsigned long long bits = M2[w];
                while (bits) {
                    int i = (w << 6) + __builtin_ctzll(bits);
                    bits &= bits - 1;
                    io0 += w3t[(size_t)i * NOUT + lane];
                    if (lane < NOUT - 64) io1 += w3t[(size_t)i * NOUT + 64 + lane];
                }
            }
            vo0 = bo0 * vo0 + (1.f - bo0) * io0;
            vo1 = bo1 * vo1 + (1.f - bo1) * io1;
            vs0 += vo0;
            vs1 += vo1;
        }
    }

    out[b * NOUT + lane] = vs0 * (1.f / (float)T_);
    if (lane < NOUT - 64) out[b * NOUT + 64 + lane] = vs1 * (1.f / (float)T_);
}

// ---------------- launch ----------------
extern "C" void kernel_launch(void* const* d_in, const int* in_sizes, int n_in,
                              void* d_out, int out_size, void* d_ws, size_t ws_size,
                              hipStream_t stream) {
    const float* x      = (const float*)d_in[0];   // [B][T][NIN]
    const float* w1     = (const float*)d_in[1];   // [H1][NIN]
    const float* w_rec  = (const float*)d_in[2];   // [H1][H1]
    const float* w2     = (const float*)d_in[3];   // [H2][H1]
    const float* w3     = (const float*)d_in[4];   // [NOUT][H2]
    const float* alpha1 = (const float*)d_in[5];
    const float* rho1   = (const float*)d_in[6];
    const float* beta_a1= (const float*)d_in[7];
    const float* alpha2 = (const float*)d_in[8];
    const float* rho2   = (const float*)d_in[9];
    const float* beta_a2= (const float*)d_in[10];
    const float* beta_out=(const float*)d_in[11];
    float* out = (float*)d_out;

    const int M = B_ * T_;                         // 19200

    size_t off = 0;
    auto take = [&](size_t bytes) {
        void* p = (char*)d_ws + off;
        off += (bytes + 255) & ~(size_t)255;
        return p;
    };
    float* I1ff = (float*)take((size_t)M * H1 * 4);            // 39.3 MB
    float* wrt  = (float*)take((size_t)H1 * H1 * 4);
    float* w2t  = (float*)take((size_t)H1 * H2 * 4);
    float* w3t  = (float*)take((size_t)H2 * NOUT * 4);
    unsigned short* xb  = (unsigned short*)take((size_t)M * KP * 2);   // 90.9 MB
    unsigned short* w1b = (unsigned short*)take((size_t)H1 * KP * 2);  // 2.4 MB
    bool use_bf16 = (off <= ws_size);

    transpose_k<<<(H1 * H1 + 255) / 256, 256, 0, stream>>>(w_rec, wrt, H1, H1);
    transpose_k<<<(H2 * H1 + 255) / 256, 256, 0, stream>>>(w2, w2t, H2, H1);
    transpose_k<<<(NOUT * H2 + 255) / 256, 256, 0, stream>>>(w3, w3t, NOUT, H2);

    if (use_bf16) {
        int nx = M * (KP / 8);
        cvt_pad_bf16<<<(nx + 255) / 256, 256, 0, stream>>>(x, xb, M, NIN, KP);
        int nw = H1 * (KP / 8);
        cvt_pad_bf16<<<(nw + 255) / 256, 256, 0, stream>>>(w1, w1b, H1, NIN, KP);

        dim3 gg(H1 / 128, M / 128);   // (4, 150) = 600 blocks (swizzle assumes 600)
        gemm_bf16<<<gg, 256, 0, stream>>>(xb, w1b, I1ff);
    } else {
        dim3 gg(H1 / GBN, M / GBM);
        gemm_ff<<<gg, 256, 0, stream>>>(x, w1, I1ff);
    }

    snn_scan_wave<<<B_, 64, 0, stream>>>(I1ff, wrt, w2t, w3t,
                                         alpha1, rho1, beta_a1,
                                         alpha2, rho2, beta_a2,
                                         beta_out, out);
}